// Round 1
// baseline (829.575 us; speedup 1.0000x reference)
//
#include <hip/hip_runtime.h>
#include <math.h>

namespace {

constexpr int Bn = 8;
constexpr int Sn = 1024;
constexpr int Dn = 256;
constexpr int Mn = Bn * Sn;   // 8192 rows

__device__ __forceinline__ float sigmoidf_(float x) {
    return 1.0f / (1.0f + __expf(-x));
}

// ---------------------------------------------------------------------------
// Fused projection GEMM: Y_m = act_m(X @ W_m^T + b_m) for m in {q,k,f,i}
// X: [M, D] row-major; W: [D, D] row-major [out,in]; tile 64x64, BK=16.
// ---------------------------------------------------------------------------
__global__ __launch_bounds__(256) void proj_gemm(
    const float* __restrict__ X,
    const float* __restrict__ W0, const float* __restrict__ b0,
    const float* __restrict__ W1, const float* __restrict__ b1,
    const float* __restrict__ W2, const float* __restrict__ b2,
    const float* __restrict__ W3, const float* __restrict__ b3,
    float* __restrict__ Y0, float* __restrict__ Y1,
    float* __restrict__ Y2, float* __restrict__ Y3)
{
    __shared__ float As[16][68];      // [k][m], padded to avoid bank conflicts
    __shared__ float Bs[4][16][68];   // [mat][k][n]

    const int tid = threadIdx.x;
    const int tx = tid & 15;          // 0..15 -> 4 cols each
    const int ty = tid >> 4;          // 0..15 -> 4 rows each
    const int mb = blockIdx.x * 64;
    const int nb = blockIdx.y * 64;
    const int lr = tid >> 2;          // 0..63 load row
    const int lk = (tid & 3) * 4;     // 0,4,8,12 load k offset

    float acc[4][4][4];
    #pragma unroll
    for (int m = 0; m < 4; ++m)
        #pragma unroll
        for (int i = 0; i < 4; ++i)
            #pragma unroll
            for (int j = 0; j < 4; ++j) acc[m][i][j] = 0.0f;

    for (int k0 = 0; k0 < Dn; k0 += 16) {
        const float4 a  = *(const float4*)(X  + (size_t)(mb + lr) * Dn + k0 + lk);
        const float4 w0 = *(const float4*)(W0 + (size_t)(nb + lr) * Dn + k0 + lk);
        const float4 w1 = *(const float4*)(W1 + (size_t)(nb + lr) * Dn + k0 + lk);
        const float4 w2 = *(const float4*)(W2 + (size_t)(nb + lr) * Dn + k0 + lk);
        const float4 w3 = *(const float4*)(W3 + (size_t)(nb + lr) * Dn + k0 + lk);
        __syncthreads();
        As[lk+0][lr] = a.x;  As[lk+1][lr] = a.y;  As[lk+2][lr] = a.z;  As[lk+3][lr] = a.w;
        Bs[0][lk+0][lr] = w0.x; Bs[0][lk+1][lr] = w0.y; Bs[0][lk+2][lr] = w0.z; Bs[0][lk+3][lr] = w0.w;
        Bs[1][lk+0][lr] = w1.x; Bs[1][lk+1][lr] = w1.y; Bs[1][lk+2][lr] = w1.z; Bs[1][lk+3][lr] = w1.w;
        Bs[2][lk+0][lr] = w2.x; Bs[2][lk+1][lr] = w2.y; Bs[2][lk+2][lr] = w2.z; Bs[2][lk+3][lr] = w2.w;
        Bs[3][lk+0][lr] = w3.x; Bs[3][lk+1][lr] = w3.y; Bs[3][lk+2][lr] = w3.z; Bs[3][lk+3][lr] = w3.w;
        __syncthreads();

        #pragma unroll
        for (int kk = 0; kk < 16; ++kk) {
            const float4 av = *(const float4*)&As[kk][ty * 4];
            const float aa[4] = {av.x, av.y, av.z, av.w};
            #pragma unroll
            for (int m = 0; m < 4; ++m) {
                const float4 bv = *(const float4*)&Bs[m][kk][tx * 4];
                const float bb[4] = {bv.x, bv.y, bv.z, bv.w};
                #pragma unroll
                for (int i = 0; i < 4; ++i)
                    #pragma unroll
                    for (int j = 0; j < 4; ++j)
                        acc[m][i][j] = fmaf(aa[i], bb[j], acc[m][i][j]);
            }
        }
    }

    const float4 bb0 = *(const float4*)(b0 + nb + tx * 4);
    const float4 bb1 = *(const float4*)(b1 + nb + tx * 4);
    const float4 bb2 = *(const float4*)(b2 + nb + tx * 4);
    const float4 bb3 = *(const float4*)(b3 + nb + tx * 4);

    #pragma unroll
    for (int i = 0; i < 4; ++i) {
        const size_t rowoff = (size_t)(mb + ty * 4 + i) * Dn + nb + tx * 4;
        float4 o;
        // q (no act)
        o.x = acc[0][i][0] + bb0.x; o.y = acc[0][i][1] + bb0.y;
        o.z = acc[0][i][2] + bb0.z; o.w = acc[0][i][3] + bb0.w;
        *(float4*)(Y0 + rowoff) = o;
        // k (no act)
        o.x = acc[1][i][0] + bb1.x; o.y = acc[1][i][1] + bb1.y;
        o.z = acc[1][i][2] + bb1.z; o.w = acc[1][i][3] + bb1.w;
        *(float4*)(Y1 + rowoff) = o;
        // f (sigmoid)
        o.x = sigmoidf_(acc[2][i][0] + bb2.x); o.y = sigmoidf_(acc[2][i][1] + bb2.y);
        o.z = sigmoidf_(acc[2][i][2] + bb2.z); o.w = sigmoidf_(acc[2][i][3] + bb2.w);
        *(float4*)(Y2 + rowoff) = o;
        // i (exp)
        o.x = __expf(acc[3][i][0] + bb3.x); o.y = __expf(acc[3][i][1] + bb3.y);
        o.z = __expf(acc[3][i][2] + bb3.z); o.w = __expf(acc[3][i][3] + bb3.w);
        *(float4*)(Y3 + rowoff) = o;
    }
}

// ---------------------------------------------------------------------------
// Output GEMM: out = H @ Wo^T + bo
// ---------------------------------------------------------------------------
__global__ __launch_bounds__(256) void out_gemm(
    const float* __restrict__ X, const float* __restrict__ W,
    const float* __restrict__ bias, float* __restrict__ Y)
{
    __shared__ float As[16][68];
    __shared__ float Bs[16][68];

    const int tid = threadIdx.x;
    const int tx = tid & 15;
    const int ty = tid >> 4;
    const int mb = blockIdx.x * 64;
    const int nb = blockIdx.y * 64;
    const int lr = tid >> 2;
    const int lk = (tid & 3) * 4;

    float acc[4][4];
    #pragma unroll
    for (int i = 0; i < 4; ++i)
        #pragma unroll
        for (int j = 0; j < 4; ++j) acc[i][j] = 0.0f;

    for (int k0 = 0; k0 < Dn; k0 += 16) {
        const float4 a = *(const float4*)(X + (size_t)(mb + lr) * Dn + k0 + lk);
        const float4 w = *(const float4*)(W + (size_t)(nb + lr) * Dn + k0 + lk);
        __syncthreads();
        As[lk+0][lr] = a.x; As[lk+1][lr] = a.y; As[lk+2][lr] = a.z; As[lk+3][lr] = a.w;
        Bs[lk+0][lr] = w.x; Bs[lk+1][lr] = w.y; Bs[lk+2][lr] = w.z; Bs[lk+3][lr] = w.w;
        __syncthreads();

        #pragma unroll
        for (int kk = 0; kk < 16; ++kk) {
            const float4 av = *(const float4*)&As[kk][ty * 4];
            const float4 bv = *(const float4*)&Bs[kk][tx * 4];
            const float aa[4] = {av.x, av.y, av.z, av.w};
            const float bb[4] = {bv.x, bv.y, bv.z, bv.w};
            #pragma unroll
            for (int i = 0; i < 4; ++i)
                #pragma unroll
                for (int j = 0; j < 4; ++j)
                    acc[i][j] = fmaf(aa[i], bb[j], acc[i][j]);
        }
    }

    const float4 bbv = *(const float4*)(bias + nb + tx * 4);
    #pragma unroll
    for (int i = 0; i < 4; ++i) {
        const size_t rowoff = (size_t)(mb + ty * 4 + i) * Dn + nb + tx * 4;
        float4 o;
        o.x = acc[i][0] + bbv.x; o.y = acc[i][1] + bbv.y;
        o.z = acc[i][2] + bbv.z; o.w = acc[i][3] + bbv.w;
        *(float4*)(Y + rowoff) = o;
    }
}

// ---------------------------------------------------------------------------
// Sequential mLSTM scan.
// Grid: (B, D/8). Block: 256 threads = 4 waves.
// Each wave owns 2 rows of C (rows r0, r0+1) spread over 64 lanes x 4 cols.
// Each thread also keeps a redundant-per-wave 4-col slice of n.
// h[t, b, r] = (C_t q_t)[r] / max(|n_t . q_t|, 1)
// ---------------------------------------------------------------------------
__global__ __launch_bounds__(256) void mlstm_scan(
    const float* __restrict__ Pf, const float* __restrict__ Pi,
    const float* __restrict__ Pk, const float* __restrict__ Pq,
    float* __restrict__ Ph)
{
    const int b    = blockIdx.x;
    const int g    = blockIdx.y;              // 0..31 row group (8 rows)
    const int tid  = threadIdx.x;
    const int lane = tid & 63;
    const int r0   = g * 8 + (tid >> 6) * 2;  // first of this wave-subgroup's 2 rows
    const int c0   = lane * 4;                // 4 columns per lane

    const size_t base = (size_t)b * Sn * Dn;
    const float* pf = Pf + base;
    const float* pI = Pi + base;
    const float* pk = Pk + base;
    const float* pq = Pq + base;
    float*       ph = Ph + base;

    float C00 = 0.f, C01 = 0.f, C02 = 0.f, C03 = 0.f;
    float C10 = 0.f, C11 = 0.f, C12 = 0.f, C13 = 0.f;
    float n0 = 0.f, n1 = 0.f, n2 = 0.f, n3 = 0.f;

    #pragma unroll 2
    for (int t = 0; t < Sn; ++t) {
        const int off = t * Dn;
        const float4 k4 = *(const float4*)(pk + off + c0);
        const float4 q4 = *(const float4*)(pq + off + c0);
        const float4 fc = *(const float4*)(pf + off + c0);
        const float4 ic = *(const float4*)(pI + off + c0);
        const float2 fr = *(const float2*)(pf + off + r0);
        const float2 ir = *(const float2*)(pI + off + r0);
        const float2 vr = *(const float2*)(pq + off + r0);   // v = q projection (Wv unused)

        // n_t = f .* n + i .* k   (per key column)
        n0 = fmaf(fc.x, n0, ic.x * k4.x);
        n1 = fmaf(fc.y, n1, ic.y * k4.y);
        n2 = fmaf(fc.z, n2, ic.z * k4.z);
        n3 = fmaf(fc.w, n3, ic.w * k4.w);
        float dp = n0 * q4.x + n1 * q4.y + n2 * q4.z + n3 * q4.w;

        // C_t[r, c] = f[r] * C[r, c] + (i[r] * v[r]) * k[c]
        const float w0 = ir.x * vr.x;
        const float w1 = ir.y * vr.y;
        C00 = fmaf(fr.x, C00, w0 * k4.x);
        C01 = fmaf(fr.x, C01, w0 * k4.y);
        C02 = fmaf(fr.x, C02, w0 * k4.z);
        C03 = fmaf(fr.x, C03, w0 * k4.w);
        C10 = fmaf(fr.y, C10, w1 * k4.x);
        C11 = fmaf(fr.y, C11, w1 * k4.y);
        C12 = fmaf(fr.y, C12, w1 * k4.z);
        C13 = fmaf(fr.y, C13, w1 * k4.w);

        float num0 = C00 * q4.x + C01 * q4.y + C02 * q4.z + C03 * q4.w;
        float num1 = C10 * q4.x + C11 * q4.y + C12 * q4.z + C13 * q4.w;

        // 64-lane butterfly reductions (results identical on all lanes)
        #pragma unroll
        for (int s = 1; s < 64; s <<= 1) {
            num0 += __shfl_xor(num0, s, 64);
            num1 += __shfl_xor(num1, s, 64);
            dp   += __shfl_xor(dp,   s, 64);
        }

        const float inv = 1.0f / fmaxf(fabsf(dp), 1.0f);
        if (lane < 2) {
            ph[off + r0 + lane] = (lane == 0 ? num0 : num1) * inv;
        }
    }
}

} // anonymous namespace

extern "C" void kernel_launch(void* const* d_in, const int* in_sizes, int n_in,
                              void* d_out, int out_size, void* d_ws, size_t ws_size,
                              hipStream_t stream)
{
    const float* x  = (const float*)d_in[0];
    const float* Wq = (const float*)d_in[1];  const float* bq = (const float*)d_in[2];
    const float* Wk = (const float*)d_in[3];  const float* bk = (const float*)d_in[4];
    // d_in[5] = Wv, d_in[6] = bv -- unused (reference uses W_q for v)
    const float* Wf = (const float*)d_in[7];  const float* bf = (const float*)d_in[8];
    const float* Wi = (const float*)d_in[9];  const float* bi = (const float*)d_in[10];
    const float* Wo = (const float*)d_in[11]; const float* bo = (const float*)d_in[12];
    float* out = (float*)d_out;

    float* ws = (float*)d_ws;
    const size_t sz = (size_t)Mn * Dn;     // 2,097,152 floats = 8 MB
    float* Pq = ws;
    float* Pk = ws + sz;
    float* Pf = ws + 2 * sz;
    float* Pi = ws + 3 * sz;
    float* Ph = ws + 4 * sz;               // total 40 MB of workspace

    proj_gemm<<<dim3(Mn / 64, Dn / 64), 256, 0, stream>>>(
        x, Wq, bq, Wk, bk, Wf, bf, Wi, bi, Pq, Pk, Pf, Pi);

    mlstm_scan<<<dim3(Bn, Dn / 8), 256, 0, stream>>>(Pf, Pi, Pk, Pq, Ph);

    out_gemm<<<dim3(Mn / 64, Dn / 64), 256, 0, stream>>>(Ph, Wo, bo, out);
}

// Round 2
// 586.984 us; speedup vs baseline: 1.4133x; 1.4133x over previous
//
#include <hip/hip_runtime.h>
#include <math.h>

namespace {

constexpr int Bn = 8;
constexpr int Sn = 1024;
constexpr int Dn = 256;
constexpr int Mn = Bn * Sn;   // 8192 rows

__device__ float g_den[Bn * Sn];   // raw n·q per (b,t); clamp applied in out_gemm

__device__ __forceinline__ float sigmoidf_(float x) {
    return 1.0f / (1.0f + __expf(-x));
}

// ---------------------------------------------------------------------------
// Fused projection GEMM: Y_m = act_m(X @ W_m^T + b_m) for m in {q,k,f,i}
// ---------------------------------------------------------------------------
__global__ __launch_bounds__(256) void proj_gemm(
    const float* __restrict__ X,
    const float* __restrict__ W0, const float* __restrict__ b0,
    const float* __restrict__ W1, const float* __restrict__ b1,
    const float* __restrict__ W2, const float* __restrict__ b2,
    const float* __restrict__ W3, const float* __restrict__ b3,
    float* __restrict__ Y0, float* __restrict__ Y1,
    float* __restrict__ Y2, float* __restrict__ Y3)
{
    __shared__ float As[16][68];
    __shared__ float Bs[4][16][68];

    const int tid = threadIdx.x;
    const int tx = tid & 15;
    const int ty = tid >> 4;
    const int mb = blockIdx.x * 64;
    const int nb = blockIdx.y * 64;
    const int lr = tid >> 2;
    const int lk = (tid & 3) * 4;

    float acc[4][4][4];
    #pragma unroll
    for (int m = 0; m < 4; ++m)
        #pragma unroll
        for (int i = 0; i < 4; ++i)
            #pragma unroll
            for (int j = 0; j < 4; ++j) acc[m][i][j] = 0.0f;

    for (int k0 = 0; k0 < Dn; k0 += 16) {
        const float4 a  = *(const float4*)(X  + (size_t)(mb + lr) * Dn + k0 + lk);
        const float4 w0 = *(const float4*)(W0 + (size_t)(nb + lr) * Dn + k0 + lk);
        const float4 w1 = *(const float4*)(W1 + (size_t)(nb + lr) * Dn + k0 + lk);
        const float4 w2 = *(const float4*)(W2 + (size_t)(nb + lr) * Dn + k0 + lk);
        const float4 w3 = *(const float4*)(W3 + (size_t)(nb + lr) * Dn + k0 + lk);
        __syncthreads();
        As[lk+0][lr] = a.x;  As[lk+1][lr] = a.y;  As[lk+2][lr] = a.z;  As[lk+3][lr] = a.w;
        Bs[0][lk+0][lr] = w0.x; Bs[0][lk+1][lr] = w0.y; Bs[0][lk+2][lr] = w0.z; Bs[0][lk+3][lr] = w0.w;
        Bs[1][lk+0][lr] = w1.x; Bs[1][lk+1][lr] = w1.y; Bs[1][lk+2][lr] = w1.z; Bs[1][lk+3][lr] = w1.w;
        Bs[2][lk+0][lr] = w2.x; Bs[2][lk+1][lr] = w2.y; Bs[2][lk+2][lr] = w2.z; Bs[2][lk+3][lr] = w2.w;
        Bs[3][lk+0][lr] = w3.x; Bs[3][lk+1][lr] = w3.y; Bs[3][lk+2][lr] = w3.z; Bs[3][lk+3][lr] = w3.w;
        __syncthreads();

        #pragma unroll
        for (int kk = 0; kk < 16; ++kk) {
            const float4 av = *(const float4*)&As[kk][ty * 4];
            const float aa[4] = {av.x, av.y, av.z, av.w};
            #pragma unroll
            for (int m = 0; m < 4; ++m) {
                const float4 bv = *(const float4*)&Bs[m][kk][tx * 4];
                const float bb[4] = {bv.x, bv.y, bv.z, bv.w};
                #pragma unroll
                for (int i = 0; i < 4; ++i)
                    #pragma unroll
                    for (int j = 0; j < 4; ++j)
                        acc[m][i][j] = fmaf(aa[i], bb[j], acc[m][i][j]);
            }
        }
    }

    const float4 bb0 = *(const float4*)(b0 + nb + tx * 4);
    const float4 bb1 = *(const float4*)(b1 + nb + tx * 4);
    const float4 bb2 = *(const float4*)(b2 + nb + tx * 4);
    const float4 bb3 = *(const float4*)(b3 + nb + tx * 4);

    #pragma unroll
    for (int i = 0; i < 4; ++i) {
        const size_t rowoff = (size_t)(mb + ty * 4 + i) * Dn + nb + tx * 4;
        float4 o;
        o.x = acc[0][i][0] + bb0.x; o.y = acc[0][i][1] + bb0.y;
        o.z = acc[0][i][2] + bb0.z; o.w = acc[0][i][3] + bb0.w;
        *(float4*)(Y0 + rowoff) = o;
        o.x = acc[1][i][0] + bb1.x; o.y = acc[1][i][1] + bb1.y;
        o.z = acc[1][i][2] + bb1.z; o.w = acc[1][i][3] + bb1.w;
        *(float4*)(Y1 + rowoff) = o;
        o.x = sigmoidf_(acc[2][i][0] + bb2.x); o.y = sigmoidf_(acc[2][i][1] + bb2.y);
        o.z = sigmoidf_(acc[2][i][2] + bb2.z); o.w = sigmoidf_(acc[2][i][3] + bb2.w);
        *(float4*)(Y2 + rowoff) = o;
        o.x = __expf(acc[3][i][0] + bb3.x); o.y = __expf(acc[3][i][1] + bb3.y);
        o.z = __expf(acc[3][i][2] + bb3.z); o.w = __expf(acc[3][i][3] + bb3.w);
        *(float4*)(Y3 + rowoff) = o;
    }
}

// ---------------------------------------------------------------------------
// Output GEMM: out = (num * invden) @ Wo^T + bo  (invden folded into A-load)
// ---------------------------------------------------------------------------
__global__ __launch_bounds__(256) void out_gemm(
    const float* __restrict__ X, const float* __restrict__ W,
    const float* __restrict__ bias, float* __restrict__ Y)
{
    __shared__ float As[16][68];
    __shared__ float Bs[16][68];

    const int tid = threadIdx.x;
    const int tx = tid & 15;
    const int ty = tid >> 4;
    const int mb = blockIdx.x * 64;
    const int nb = blockIdx.y * 64;
    const int lr = tid >> 2;
    const int lk = (tid & 3) * 4;

    // per-row inverse denominator (row m = b*1024 + t maps 1:1 to g_den[m])
    const float dn   = g_den[mb + lr];
    const float invd = 1.0f / fmaxf(fabsf(dn), 1.0f);

    float acc[4][4];
    #pragma unroll
    for (int i = 0; i < 4; ++i)
        #pragma unroll
        for (int j = 0; j < 4; ++j) acc[i][j] = 0.0f;

    for (int k0 = 0; k0 < Dn; k0 += 16) {
        float4 a = *(const float4*)(X + (size_t)(mb + lr) * Dn + k0 + lk);
        const float4 w = *(const float4*)(W + (size_t)(nb + lr) * Dn + k0 + lk);
        a.x *= invd; a.y *= invd; a.z *= invd; a.w *= invd;
        __syncthreads();
        As[lk+0][lr] = a.x; As[lk+1][lr] = a.y; As[lk+2][lr] = a.z; As[lk+3][lr] = a.w;
        Bs[lk+0][lr] = w.x; Bs[lk+1][lr] = w.y; Bs[lk+2][lr] = w.z; Bs[lk+3][lr] = w.w;
        __syncthreads();

        #pragma unroll
        for (int kk = 0; kk < 16; ++kk) {
            const float4 av = *(const float4*)&As[kk][ty * 4];
            const float4 bv = *(const float4*)&Bs[kk][tx * 4];
            const float aa[4] = {av.x, av.y, av.z, av.w};
            const float bb[4] = {bv.x, bv.y, bv.z, bv.w};
            #pragma unroll
            for (int i = 0; i < 4; ++i)
                #pragma unroll
                for (int j = 0; j < 4; ++j)
                    acc[i][j] = fmaf(aa[i], bb[j], acc[i][j]);
        }
    }

    const float4 bbv = *(const float4*)(bias + nb + tx * 4);
    #pragma unroll
    for (int i = 0; i < 4; ++i) {
        const size_t rowoff = (size_t)(mb + ty * 4 + i) * Dn + nb + tx * 4;
        float4 o;
        o.x = acc[i][0] + bbv.x; o.y = acc[i][1] + bbv.y;
        o.z = acc[i][2] + bbv.z; o.w = acc[i][3] + bbv.w;
        *(float4*)(Y + rowoff) = o;
    }
}

// ---------------------------------------------------------------------------
// Merged scan + den kernel. Grid (33, B).
//  blockIdx.x < 32 : C-scan for 8 rows, writes RAW numerators to Pnum.
//                    Reductions batched 8 steps deep (16 interleaved chains).
//  blockIdx.x == 32: normalizer scan, writes raw n·q to g_den (8 blocks).
// ---------------------------------------------------------------------------
__global__ __launch_bounds__(256) void scan_den(
    const float* __restrict__ Pf, const float* __restrict__ Pi,
    const float* __restrict__ Pk, const float* __restrict__ Pq,
    float* __restrict__ Pnum)
{
    __shared__ float lds[4][16];

    const int b   = blockIdx.y;
    const int gx  = blockIdx.x;
    const size_t base = (size_t)b * Sn * Dn;

    if (gx == 32) {
        // ----- normalizer / denominator duty -----
        const int c    = threadIdx.x;       // column 0..255
        const int lane = c & 63;
        const int w    = c >> 6;
        const float* pf = Pf + base;
        const float* pI = Pi + base;
        const float* pk = Pk + base;
        const float* pq = Pq + base;

        float n = 0.0f;
        for (int t0 = 0; t0 < Sn; t0 += 16) {
            float p[16];
            #pragma unroll
            for (int j = 0; j < 16; ++j) {
                const int off = (t0 + j) * Dn + c;
                const float f = pf[off];
                const float i = pI[off];
                const float k = pk[off];
                const float q = pq[off];
                n = fmaf(f, n, i * k);
                p[j] = n * q;
            }
            #pragma unroll
            for (int s = 1; s < 64; s <<= 1)
                #pragma unroll
                for (int j = 0; j < 16; ++j)
                    p[j] += __shfl_xor(p[j], s, 64);
            if (lane == 0) {
                #pragma unroll
                for (int j = 0; j < 16; ++j) lds[w][j] = p[j];
            }
            __syncthreads();
            if (c < 16) {
                g_den[b * Sn + t0 + c] = lds[0][c] + lds[1][c] + lds[2][c] + lds[3][c];
            }
            __syncthreads();
        }
        return;
    }

    // ----- C-matrix scan duty: 8 rows per block, 2 rows per wave -----
    const int tid  = threadIdx.x;
    const int lane = tid & 63;
    const int r0   = gx * 8 + (tid >> 6) * 2;
    const int c0   = lane * 4;

    const float* pf = Pf + base;
    const float* pI = Pi + base;
    const float* pk = Pk + base;
    const float* pq = Pq + base;
    float*     pnum = Pnum + base;

    float C00 = 0.f, C01 = 0.f, C02 = 0.f, C03 = 0.f;
    float C10 = 0.f, C11 = 0.f, C12 = 0.f, C13 = 0.f;

    for (int t0 = 0; t0 < Sn; t0 += 8) {
        float m0[8], m1[8];
        #pragma unroll
        for (int j = 0; j < 8; ++j) {
            const int off = (t0 + j) * Dn;
            const float4 k4 = *(const float4*)(pk + off + c0);
            const float4 q4 = *(const float4*)(pq + off + c0);
            const float2 fr = *(const float2*)(pf + off + r0);
            const float2 ir = *(const float2*)(pI + off + r0);
            const float2 vr = *(const float2*)(pq + off + r0);   // v = q projection

            const float w0 = ir.x * vr.x;
            const float w1 = ir.y * vr.y;
            C00 = fmaf(fr.x, C00, w0 * k4.x);
            C01 = fmaf(fr.x, C01, w0 * k4.y);
            C02 = fmaf(fr.x, C02, w0 * k4.z);
            C03 = fmaf(fr.x, C03, w0 * k4.w);
            C10 = fmaf(fr.y, C10, w1 * k4.x);
            C11 = fmaf(fr.y, C11, w1 * k4.y);
            C12 = fmaf(fr.y, C12, w1 * k4.z);
            C13 = fmaf(fr.y, C13, w1 * k4.w);

            float a0 = C00 * q4.x;
            a0 = fmaf(C01, q4.y, a0);
            a0 = fmaf(C02, q4.z, a0);
            a0 = fmaf(C03, q4.w, a0);
            float a1 = C10 * q4.x;
            a1 = fmaf(C11, q4.y, a1);
            a1 = fmaf(C12, q4.z, a1);
            a1 = fmaf(C13, q4.w, a1);
            m0[j] = a0;
            m1[j] = a1;
        }

        // 16 independent butterfly chains, interleaved for latency hiding
        #pragma unroll
        for (int s = 1; s < 64; s <<= 1) {
            #pragma unroll
            for (int j = 0; j < 8; ++j) {
                m0[j] += __shfl_xor(m0[j], s, 64);
                m1[j] += __shfl_xor(m1[j], s, 64);
            }
        }

        if (lane < 2) {
            #pragma unroll
            for (int j = 0; j < 8; ++j) {
                pnum[(t0 + j) * Dn + r0 + lane] = (lane == 0 ? m0[j] : m1[j]);
            }
        }
    }
}

} // anonymous namespace

extern "C" void kernel_launch(void* const* d_in, const int* in_sizes, int n_in,
                              void* d_out, int out_size, void* d_ws, size_t ws_size,
                              hipStream_t stream)
{
    const float* x  = (const float*)d_in[0];
    const float* Wq = (const float*)d_in[1];  const float* bq = (const float*)d_in[2];
    const float* Wk = (const float*)d_in[3];  const float* bk = (const float*)d_in[4];
    // d_in[5]=Wv, d_in[6]=bv unused (reference uses W_q for v)
    const float* Wf = (const float*)d_in[7];  const float* bf = (const float*)d_in[8];
    const float* Wi = (const float*)d_in[9];  const float* bi = (const float*)d_in[10];
    const float* Wo = (const float*)d_in[11]; const float* bo = (const float*)d_in[12];
    float* out = (float*)d_out;

    float* ws = (float*)d_ws;
    const size_t sz = (size_t)Mn * Dn;     // 8 MB each
    float* Pq = ws;
    float* Pk = ws + sz;
    float* Pf = ws + 2 * sz;
    float* Pi = ws + 3 * sz;
    float* Pn = ws + 4 * sz;               // raw numerators

    proj_gemm<<<dim3(Mn / 64, Dn / 64), 256, 0, stream>>>(
        x, Wq, bq, Wk, bk, Wf, bf, Wi, bi, Pq, Pk, Pf, Pi);

    scan_den<<<dim3(33, Bn), 256, 0, stream>>>(Pf, Pi, Pk, Pq, Pn);

    out_gemm<<<dim3(Mn / 64, Dn / 64), 256, 0, stream>>>(Pn, Wo, bo, out);
}

// Round 3
// 553.302 us; speedup vs baseline: 1.4993x; 1.0609x over previous
//
#include <hip/hip_runtime.h>
#include <math.h>

namespace {

constexpr int Bn = 8;
constexpr int Sn = 1024;
constexpr int Dn = 256;
constexpr int Mn = Bn * Sn;   // 8192 rows

__device__ float g_den[Bn * Sn];   // raw n·q per (b,t); clamp applied in out_gemm

__device__ __forceinline__ float sigmoidf_(float x) {
    return 1.0f / (1.0f + __expf(-x));
}

// ---------------------------------------------------------------------------
// Fused projection GEMM: Y_m = act_m(X @ W_m^T + b_m) for m in {q,k,f,i}
// ---------------------------------------------------------------------------
__global__ __launch_bounds__(256) void proj_gemm(
    const float* __restrict__ X,
    const float* __restrict__ W0, const float* __restrict__ b0,
    const float* __restrict__ W1, const float* __restrict__ b1,
    const float* __restrict__ W2, const float* __restrict__ b2,
    const float* __restrict__ W3, const float* __restrict__ b3,
    float* __restrict__ Y0, float* __restrict__ Y1,
    float* __restrict__ Y2, float* __restrict__ Y3)
{
    __shared__ float As[16][68];
    __shared__ float Bs[4][16][68];

    const int tid = threadIdx.x;
    const int tx = tid & 15;
    const int ty = tid >> 4;
    const int mb = blockIdx.x * 64;
    const int nb = blockIdx.y * 64;
    const int lr = tid >> 2;
    const int lk = (tid & 3) * 4;

    float acc[4][4][4];
    #pragma unroll
    for (int m = 0; m < 4; ++m)
        #pragma unroll
        for (int i = 0; i < 4; ++i)
            #pragma unroll
            for (int j = 0; j < 4; ++j) acc[m][i][j] = 0.0f;

    for (int k0 = 0; k0 < Dn; k0 += 16) {
        const float4 a  = *(const float4*)(X  + (size_t)(mb + lr) * Dn + k0 + lk);
        const float4 w0 = *(const float4*)(W0 + (size_t)(nb + lr) * Dn + k0 + lk);
        const float4 w1 = *(const float4*)(W1 + (size_t)(nb + lr) * Dn + k0 + lk);
        const float4 w2 = *(const float4*)(W2 + (size_t)(nb + lr) * Dn + k0 + lk);
        const float4 w3 = *(const float4*)(W3 + (size_t)(nb + lr) * Dn + k0 + lk);
        __syncthreads();
        As[lk+0][lr] = a.x;  As[lk+1][lr] = a.y;  As[lk+2][lr] = a.z;  As[lk+3][lr] = a.w;
        Bs[0][lk+0][lr] = w0.x; Bs[0][lk+1][lr] = w0.y; Bs[0][lk+2][lr] = w0.z; Bs[0][lk+3][lr] = w0.w;
        Bs[1][lk+0][lr] = w1.x; Bs[1][lk+1][lr] = w1.y; Bs[1][lk+2][lr] = w1.z; Bs[1][lk+3][lr] = w1.w;
        Bs[2][lk+0][lr] = w2.x; Bs[2][lk+1][lr] = w2.y; Bs[2][lk+2][lr] = w2.z; Bs[2][lk+3][lr] = w2.w;
        Bs[3][lk+0][lr] = w3.x; Bs[3][lk+1][lr] = w3.y; Bs[3][lk+2][lr] = w3.z; Bs[3][lk+3][lr] = w3.w;
        __syncthreads();

        #pragma unroll
        for (int kk = 0; kk < 16; ++kk) {
            const float4 av = *(const float4*)&As[kk][ty * 4];
            const float aa[4] = {av.x, av.y, av.z, av.w};
            #pragma unroll
            for (int m = 0; m < 4; ++m) {
                const float4 bv = *(const float4*)&Bs[m][kk][tx * 4];
                const float bb[4] = {bv.x, bv.y, bv.z, bv.w};
                #pragma unroll
                for (int i = 0; i < 4; ++i)
                    #pragma unroll
                    for (int j = 0; j < 4; ++j)
                        acc[m][i][j] = fmaf(aa[i], bb[j], acc[m][i][j]);
            }
        }
    }

    const float4 bb0 = *(const float4*)(b0 + nb + tx * 4);
    const float4 bb1 = *(const float4*)(b1 + nb + tx * 4);
    const float4 bb2 = *(const float4*)(b2 + nb + tx * 4);
    const float4 bb3 = *(const float4*)(b3 + nb + tx * 4);

    #pragma unroll
    for (int i = 0; i < 4; ++i) {
        const size_t rowoff = (size_t)(mb + ty * 4 + i) * Dn + nb + tx * 4;
        float4 o;
        o.x = acc[0][i][0] + bb0.x; o.y = acc[0][i][1] + bb0.y;
        o.z = acc[0][i][2] + bb0.z; o.w = acc[0][i][3] + bb0.w;
        *(float4*)(Y0 + rowoff) = o;
        o.x = acc[1][i][0] + bb1.x; o.y = acc[1][i][1] + bb1.y;
        o.z = acc[1][i][2] + bb1.z; o.w = acc[1][i][3] + bb1.w;
        *(float4*)(Y1 + rowoff) = o;
        o.x = sigmoidf_(acc[2][i][0] + bb2.x); o.y = sigmoidf_(acc[2][i][1] + bb2.y);
        o.z = sigmoidf_(acc[2][i][2] + bb2.z); o.w = sigmoidf_(acc[2][i][3] + bb2.w);
        *(float4*)(Y2 + rowoff) = o;
        o.x = __expf(acc[3][i][0] + bb3.x); o.y = __expf(acc[3][i][1] + bb3.y);
        o.z = __expf(acc[3][i][2] + bb3.z); o.w = __expf(acc[3][i][3] + bb3.w);
        *(float4*)(Y3 + rowoff) = o;
    }
}

// ---------------------------------------------------------------------------
// Output GEMM: out = (num * invden) @ Wo^T + bo  (invden folded into A-load)
// ---------------------------------------------------------------------------
__global__ __launch_bounds__(256) void out_gemm(
    const float* __restrict__ X, const float* __restrict__ W,
    const float* __restrict__ bias, float* __restrict__ Y)
{
    __shared__ float As[16][68];
    __shared__ float Bs[16][68];

    const int tid = threadIdx.x;
    const int tx = tid & 15;
    const int ty = tid >> 4;
    const int mb = blockIdx.x * 64;
    const int nb = blockIdx.y * 64;
    const int lr = tid >> 2;
    const int lk = (tid & 3) * 4;

    const float dn   = g_den[mb + lr];
    const float invd = 1.0f / fmaxf(fabsf(dn), 1.0f);

    float acc[4][4];
    #pragma unroll
    for (int i = 0; i < 4; ++i)
        #pragma unroll
        for (int j = 0; j < 4; ++j) acc[i][j] = 0.0f;

    for (int k0 = 0; k0 < Dn; k0 += 16) {
        float4 a = *(const float4*)(X + (size_t)(mb + lr) * Dn + k0 + lk);
        const float4 w = *(const float4*)(W + (size_t)(nb + lr) * Dn + k0 + lk);
        a.x *= invd; a.y *= invd; a.z *= invd; a.w *= invd;
        __syncthreads();
        As[lk+0][lr] = a.x; As[lk+1][lr] = a.y; As[lk+2][lr] = a.z; As[lk+3][lr] = a.w;
        Bs[lk+0][lr] = w.x; Bs[lk+1][lr] = w.y; Bs[lk+2][lr] = w.z; Bs[lk+3][lr] = w.w;
        __syncthreads();

        #pragma unroll
        for (int kk = 0; kk < 16; ++kk) {
            const float4 av = *(const float4*)&As[kk][ty * 4];
            const float4 bv = *(const float4*)&Bs[kk][tx * 4];
            const float aa[4] = {av.x, av.y, av.z, av.w};
            const float bb[4] = {bv.x, bv.y, bv.z, bv.w};
            #pragma unroll
            for (int i = 0; i < 4; ++i)
                #pragma unroll
                for (int j = 0; j < 4; ++j)
                    acc[i][j] = fmaf(aa[i], bb[j], acc[i][j]);
        }
    }

    const float4 bbv = *(const float4*)(bias + nb + tx * 4);
    #pragma unroll
    for (int i = 0; i < 4; ++i) {
        const size_t rowoff = (size_t)(mb + ty * 4 + i) * Dn + nb + tx * 4;
        float4 o;
        o.x = acc[i][0] + bbv.x; o.y = acc[i][1] + bbv.y;
        o.z = acc[i][2] + bbv.z; o.w = acc[i][3] + bbv.w;
        *(float4*)(Y + rowoff) = o;
    }
}

// ---------------------------------------------------------------------------
// Merged scan + den kernel. Grid (33, B), __launch_bounds__(256,2) so the
// compiler has up to 256 VGPRs: all chunk loads are hoisted into register
// arrays for deep MLP (round-2's 44-VGPR version serialized the loads).
// ---------------------------------------------------------------------------
__global__ __launch_bounds__(256, 2) void scan_den(
    const float* __restrict__ Pf, const float* __restrict__ Pi,
    const float* __restrict__ Pk, const float* __restrict__ Pq,
    float* __restrict__ Pnum)
{
    __shared__ float lds[4][16];

    const int b   = blockIdx.y;
    const int gx  = blockIdx.x;
    const size_t base = (size_t)b * Sn * Dn;

    if (gx == 32) {
        // ----- normalizer / denominator duty -----
        const int c    = threadIdx.x;       // column 0..255
        const int lane = c & 63;
        const int w    = c >> 6;
        const float* pf = Pf + base;
        const float* pI = Pi + base;
        const float* pk = Pk + base;
        const float* pq = Pq + base;

        float n = 0.0f;
        for (int t0 = 0; t0 < Sn; t0 += 16) {
            float lf[16], li[16], lkv[16], lq[16];
            #pragma unroll
            for (int j = 0; j < 16; ++j) {
                const int off = (t0 + j) * Dn + c;
                lf[j]  = pf[off];
                li[j]  = pI[off];
                lkv[j] = pk[off];
                lq[j]  = pq[off];
            }
            float p[16];
            #pragma unroll
            for (int j = 0; j < 16; ++j) {
                n = fmaf(lf[j], n, li[j] * lkv[j]);
                p[j] = n * lq[j];
            }
            #pragma unroll
            for (int s = 1; s < 64; s <<= 1)
                #pragma unroll
                for (int j = 0; j < 16; ++j)
                    p[j] += __shfl_xor(p[j], s, 64);
            if (lane == 0) {
                #pragma unroll
                for (int j = 0; j < 16; ++j) lds[w][j] = p[j];
            }
            __syncthreads();
            if (c < 16) {
                g_den[b * Sn + t0 + c] = lds[0][c] + lds[1][c] + lds[2][c] + lds[3][c];
            }
            __syncthreads();
        }
        return;
    }

    // ----- C-matrix scan duty: 8 rows per block, 2 rows per wave -----
    const int tid  = threadIdx.x;
    const int lane = tid & 63;
    const int r0   = gx * 8 + (tid >> 6) * 2;
    const int c0   = lane * 4;

    const float* pf = Pf + base;
    const float* pI = Pi + base;
    const float* pk = Pk + base;
    const float* pq = Pq + base;
    float*     pnum = Pnum + base;

    float C00 = 0.f, C01 = 0.f, C02 = 0.f, C03 = 0.f;
    float C10 = 0.f, C11 = 0.f, C12 = 0.f, C13 = 0.f;

    for (int t0 = 0; t0 < Sn; t0 += 8) {
        // ---- phase 1: issue all loads for the chunk (deep MLP) ----
        float4 k4[8], q4[8];
        float2 fr[8], ir[8], vr[8];
        #pragma unroll
        for (int j = 0; j < 8; ++j) {
            const int off = (t0 + j) * Dn;
            k4[j] = *(const float4*)(pk + off + c0);
            q4[j] = *(const float4*)(pq + off + c0);
            fr[j] = *(const float2*)(pf + off + r0);
            ir[j] = *(const float2*)(pI + off + r0);
            vr[j] = *(const float2*)(pq + off + r0);   // v = q projection
        }

        // ---- phase 2: C-chain + per-lane dot partials ----
        float m0[8], m1[8];
        #pragma unroll
        for (int j = 0; j < 8; ++j) {
            const float w0 = ir[j].x * vr[j].x;
            const float w1 = ir[j].y * vr[j].y;
            C00 = fmaf(fr[j].x, C00, w0 * k4[j].x);
            C01 = fmaf(fr[j].x, C01, w0 * k4[j].y);
            C02 = fmaf(fr[j].x, C02, w0 * k4[j].z);
            C03 = fmaf(fr[j].x, C03, w0 * k4[j].w);
            C10 = fmaf(fr[j].y, C10, w1 * k4[j].x);
            C11 = fmaf(fr[j].y, C11, w1 * k4[j].y);
            C12 = fmaf(fr[j].y, C12, w1 * k4[j].z);
            C13 = fmaf(fr[j].y, C13, w1 * k4[j].w);

            float a0 = C00 * q4[j].x;
            a0 = fmaf(C01, q4[j].y, a0);
            a0 = fmaf(C02, q4[j].z, a0);
            a0 = fmaf(C03, q4[j].w, a0);
            float a1 = C10 * q4[j].x;
            a1 = fmaf(C11, q4[j].y, a1);
            a1 = fmaf(C12, q4[j].z, a1);
            a1 = fmaf(C13, q4[j].w, a1);
            m0[j] = a0;
            m1[j] = a1;
        }

        // ---- phase 3: 16 interleaved butterfly chains ----
        #pragma unroll
        for (int s = 1; s < 64; s <<= 1) {
            #pragma unroll
            for (int j = 0; j < 8; ++j) {
                m0[j] += __shfl_xor(m0[j], s, 64);
                m1[j] += __shfl_xor(m1[j], s, 64);
            }
        }

        // ---- phase 4: store ----
        if (lane < 2) {
            #pragma unroll
            for (int j = 0; j < 8; ++j) {
                pnum[(t0 + j) * Dn + r0 + lane] = (lane == 0 ? m0[j] : m1[j]);
            }
        }
    }
}

} // anonymous namespace

extern "C" void kernel_launch(void* const* d_in, const int* in_sizes, int n_in,
                              void* d_out, int out_size, void* d_ws, size_t ws_size,
                              hipStream_t stream)
{
    const float* x  = (const float*)d_in[0];
    const float* Wq = (const float*)d_in[1];  const float* bq = (const float*)d_in[2];
    const float* Wk = (const float*)d_in[3];  const float* bk = (const float*)d_in[4];
    // d_in[5]=Wv, d_in[6]=bv unused (reference uses W_q for v)
    const float* Wf = (const float*)d_in[7];  const float* bf = (const float*)d_in[8];
    const float* Wi = (const float*)d_in[9];  const float* bi = (const float*)d_in[10];
    const float* Wo = (const float*)d_in[11]; const float* bo = (const float*)d_in[12];
    float* out = (float*)d_out;

    float* ws = (float*)d_ws;
    const size_t sz = (size_t)Mn * Dn;     // 8 MB each
    float* Pq = ws;
    float* Pk = ws + sz;
    float* Pf = ws + 2 * sz;
    float* Pi = ws + 3 * sz;
    float* Pn = ws + 4 * sz;               // raw numerators

    proj_gemm<<<dim3(Mn / 64, Dn / 64), 256, 0, stream>>>(
        x, Wq, bq, Wk, bk, Wf, bf, Wi, bi, Pq, Pk, Pf, Pi);

    scan_den<<<dim3(33, Bn), 256, 0, stream>>>(Pf, Pi, Pk, Pq, Pn);

    out_gemm<<<dim3(Mn / 64, Dn / 64), 256, 0, stream>>>(Pn, Wo, bo, out);
}